// Round 2
// baseline (170.386 us; speedup 1.0000x reference)
//
#include <hip/hip_runtime.h>

#define NLEV 8
#define BASE 512
#define FEAT 16

// float offset of mip level k (k>=1) inside ws
__host__ __device__ __forceinline__ long mip_off(int k) {
    return 4194304L - (4194304L >> (2 * k - 2));
}

// Downsample: dst (3, r2, r2, 16) = 2x2 box filter of src (3, 2*r2, 2*r2, 16).
// One thread per float4 feature-group of one output texel.
__global__ __launch_bounds__(256) void ds_kernel(const float* __restrict__ src,
                                                 float* __restrict__ dst, int r2) {
    int idx = blockIdx.x * blockDim.x + threadIdx.x;
    int total = 3 * r2 * r2 * 4;
    if (idx >= total) return;
    int fg = idx & 3;
    int rest = idx >> 2;
    int u = rest % r2; rest /= r2;
    int v = rest % r2;
    int p = rest / r2;
    int rs = r2 * 2;
    const float4* s4 = (const float4*)src;
    long i00 = (((long)p * rs + 2 * v) * rs + 2 * u) * 4 + fg;
    long i01 = i00 + 4;              // u+1
    long i10 = i00 + (long)rs * 4;   // v+1
    long i11 = i10 + 4;
    float4 a = s4[i00], b = s4[i01], c = s4[i10], d = s4[i11];
    float4 o;
    o.x = (a.x + b.x + c.x + d.x) * 0.25f;
    o.y = (a.y + b.y + c.y + d.y) * 0.25f;
    o.z = (a.z + b.z + c.z + d.z) * 0.25f;
    o.w = (a.w + b.w + c.w + d.w) * 0.25f;
    float4* d4 = (float4*)dst;
    d4[(((long)p * r2 + v) * r2 + u) * 4 + fg] = o;
}

// Sampling: 4 threads per point; lane fg owns feature float4 [fg*4 .. fg*4+3].
// All 24 texel gathers are issued before any weighting math (ILP over latency).
__global__ __launch_bounds__(256) void tm_sample(const float* __restrict__ x,
                                                 const float* __restrict__ level,
                                                 const float* __restrict__ tex0,
                                                 const float* __restrict__ ws,
                                                 float* __restrict__ out, int n) {
    int t = blockIdx.x * blockDim.x + threadIdx.x;
    int i = t >> 2;
    if (i >= n) return;
    int fg = t & 3;

    float px = x[3 * i + 0];
    float py = x[3 * i + 1];
    float pz = x[3 * i + 2];
    float lev = fminf(fmaxf(level[i], 0.0f), (float)(NLEV - 1));
    float l0f = floorf(lev);
    float frac = lev - l0f;
    int l0 = (int)l0f;

    int kk[2];
    kk[0] = l0;
    kk[1] = min(l0 + 1, NLEV - 1);
    float lw[2];
    lw[0] = 1.0f - frac;
    lw[1] = frac;

    float uu[3] = {py, px, px};
    float vv[3] = {pz, pz, py};

    float4 tv[2][3][4];   // all texel data, static-indexed -> registers
    float fuv[2][3][2];   // fractional weights per (level, plane)

#pragma unroll
    for (int s = 0; s < 2; ++s) {
        int k = kk[s];
        int r = BASE >> k;
        float rf = (float)r;
        const float* tex = (k == 0) ? tex0 : (ws + mip_off(k));
        const float4* t4 = (const float4*)tex;
#pragma unroll
        for (int p = 0; p < 3; ++p) {
            float cu = uu[p] * rf - 0.5f;
            float cv = vv[p] * rf - 0.5f;
            float fu0 = floorf(cu), fv0 = floorf(cv);
            fuv[s][p][0] = cu - fu0;
            fuv[s][p][1] = cv - fv0;
            int iu0 = (int)fu0, iv0 = (int)fv0;
            int u0 = min(max(iu0, 0), r - 1);
            int u1 = min(max(iu0 + 1, 0), r - 1);
            int v0 = min(max(iv0, 0), r - 1);
            int v1 = min(max(iv0 + 1, 0), r - 1);
            long pb = (long)p * r * r;
            tv[s][p][0] = t4[(pb + (long)v0 * r + u0) * 4 + fg];
            tv[s][p][1] = t4[(pb + (long)v0 * r + u1) * 4 + fg];
            tv[s][p][2] = t4[(pb + (long)v1 * r + u0) * 4 + fg];
            tv[s][p][3] = t4[(pb + (long)v1 * r + u1) * 4 + fg];
        }
    }

    float4 acc[3];
#pragma unroll
    for (int p = 0; p < 3; ++p) acc[p] = make_float4(0.f, 0.f, 0.f, 0.f);

#pragma unroll
    for (int s = 0; s < 2; ++s) {
#pragma unroll
        for (int p = 0; p < 3; ++p) {
            float fu = fuv[s][p][0], fv = fuv[s][p][1];
            float w = lw[s];
            float w00 = (1.0f - fu) * (1.0f - fv) * w;
            float w01 = fu * (1.0f - fv) * w;
            float w10 = (1.0f - fu) * fv * w;
            float w11 = fu * fv * w;
            acc[p].x += tv[s][p][0].x * w00 + tv[s][p][1].x * w01 + tv[s][p][2].x * w10 + tv[s][p][3].x * w11;
            acc[p].y += tv[s][p][0].y * w00 + tv[s][p][1].y * w01 + tv[s][p][2].y * w10 + tv[s][p][3].y * w11;
            acc[p].z += tv[s][p][0].z * w00 + tv[s][p][1].z * w01 + tv[s][p][2].z * w10 + tv[s][p][3].z * w11;
            acc[p].w += tv[s][p][0].w * w00 + tv[s][p][1].w * w01 + tv[s][p][2].w * w10 + tv[s][p][3].w * w11;
        }
    }

    float4* o4 = (float4*)out;
    long ob = (long)i * 12 + fg;
    o4[ob + 0] = acc[0];
    o4[ob + 4] = acc[1];
    o4[ob + 8] = acc[2];
}

extern "C" void kernel_launch(void* const* d_in, const int* in_sizes, int n_in,
                              void* d_out, int out_size, void* d_ws, size_t ws_size,
                              hipStream_t stream) {
    const float* x     = (const float*)d_in[0];
    const float* level = (const float*)d_in[1];
    const float* tex   = (const float*)d_in[2];
    float* out = (float*)d_out;
    float* ws  = (float*)d_ws;
    int n = in_sizes[0] / 3;

    // Build mip pyramid: level k from level k-1.
    const float* src = tex;
    for (int k = 1; k < NLEV; ++k) {
        int r2 = BASE >> k;
        float* dst = ws + mip_off(k);
        int total = 3 * r2 * r2 * 4;
        int blocks = (total + 255) / 256;
        ds_kernel<<<blocks, 256, 0, stream>>>(src, dst, r2);
        src = dst;
    }

    long tt = (long)n * 4;
    int blocks = (int)((tt + 255) / 256);
    tm_sample<<<blocks, 256, 0, stream>>>(x, level, tex, ws, out, n);
}

// Round 3
// 159.078 us; speedup vs baseline: 1.0711x; 1.0711x over previous
//
#include <hip/hip_runtime.h>

#define NLEV 8
#define BASE 512
#define FEAT 16

typedef float f4v __attribute__((ext_vector_type(4)));

// float offset of mip level k (k>=1) inside ws
__host__ __device__ __forceinline__ long mip_off(int k) {
    return 4194304L - (4194304L >> (2 * k - 2));
}

// Downsample: dst (3, r2, r2, 16) = 2x2 box filter of src (3, 2*r2, 2*r2, 16).
__global__ __launch_bounds__(256) void ds_kernel(const float* __restrict__ src,
                                                 float* __restrict__ dst, int r2) {
    int idx = blockIdx.x * blockDim.x + threadIdx.x;
    int total = 3 * r2 * r2 * 4;
    if (idx >= total) return;
    int fg = idx & 3;
    int rest = idx >> 2;
    int u = rest % r2; rest /= r2;
    int v = rest % r2;
    int p = rest / r2;
    int rs = r2 * 2;
    const float4* s4 = (const float4*)src;
    long i00 = (((long)p * rs + 2 * v) * rs + 2 * u) * 4 + fg;
    long i01 = i00 + 4;
    long i10 = i00 + (long)rs * 4;
    long i11 = i10 + 4;
    float4 a = s4[i00], b = s4[i01], c = s4[i10], d = s4[i11];
    float4 o;
    o.x = (a.x + b.x + c.x + d.x) * 0.25f;
    o.y = (a.y + b.y + c.y + d.y) * 0.25f;
    o.z = (a.z + b.z + c.z + d.z) * 0.25f;
    o.w = (a.w + b.w + c.w + d.w) * 0.25f;
    float4* d4 = (float4*)dst;
    d4[(((long)p * r2 + v) * r2 + u) * 4 + fg] = o;
}

// Sampling: 8 lanes per point. lane = i*8 + usel*4 + fg.
// fg owns feature float4 [fg*4..fg*4+3]; usel owns u-column (u0 or u1).
// Neighbor lanes (fg 0..3, fixed usel) read one contiguous 64B texel; the
// usel pair covers the contiguous 128B (u0,u1) texel pair in ONE instruction.
__global__ __launch_bounds__(256) void tm_sample8(const float* __restrict__ x,
                                                  const float* __restrict__ level,
                                                  const float* __restrict__ tex0,
                                                  const float* __restrict__ ws,
                                                  float* __restrict__ out, int n) {
    int t = blockIdx.x * blockDim.x + threadIdx.x;
    int i = t >> 3;
    if (i >= n) return;
    int fg = t & 3;
    int usel = (t >> 2) & 1;

    float px = x[3 * i + 0];
    float py = x[3 * i + 1];
    float pz = x[3 * i + 2];
    float lev = fminf(fmaxf(level[i], 0.0f), (float)(NLEV - 1));
    float l0f = floorf(lev);
    float frac = lev - l0f;
    int l0 = (int)l0f;
    int k1 = min(l0 + 1, NLEV - 1);   // k1 >= 1 always

    float uu[3] = {py, px, px};
    float vv[3] = {pz, pz, py};

    const float* texs[2];
    texs[0] = (l0 == 0) ? tex0 : (ws + mip_off(l0));
    texs[1] = ws + mip_off(k1);
    int rr[2] = {BASE >> l0, BASE >> k1};

    float4 tv[2][3][2];   // [lev][plane][vrow] - this lane's u-column texels
    float wu[2][3];       // lane's u weight
    float fvv[2][3];      // v fraction

#pragma unroll
    for (int s = 0; s < 2; ++s) {
        int r = rr[s];
        float rf = (float)r;
        const float4* t4 = (const float4*)texs[s];
#pragma unroll
        for (int p = 0; p < 3; ++p) {
            float cu = uu[p] * rf - 0.5f;
            float cv = vv[p] * rf - 0.5f;
            float fu0 = floorf(cu), fv0 = floorf(cv);
            float fu = cu - fu0, fv = cv - fv0;
            int iu0 = (int)fu0, iv0 = (int)fv0;
            int u0 = min(max(iu0, 0), r - 1);
            int u1 = min(max(iu0 + 1, 0), r - 1);
            int v0 = min(max(iv0, 0), r - 1);
            int v1 = min(max(iv0 + 1, 0), r - 1);
            int u = usel ? u1 : u0;
            wu[s][p] = usel ? fu : (1.0f - fu);
            fvv[s][p] = fv;
            long pb = (long)p * r * r;
            tv[s][p][0] = t4[(pb + (long)v0 * r + u) * 4 + fg];
            tv[s][p][1] = t4[(pb + (long)v1 * r + u) * 4 + fg];
        }
    }

    float lw[2] = {1.0f - frac, frac};
    float4 res[3];
#pragma unroll
    for (int p = 0; p < 3; ++p) {
        float ax = 0.f, ay = 0.f, az = 0.f, aw = 0.f;
#pragma unroll
        for (int s = 0; s < 2; ++s) {
            float w0 = (1.0f - fvv[s][p]) * wu[s][p] * lw[s];
            float w1 = fvv[s][p] * wu[s][p] * lw[s];
            ax += tv[s][p][0].x * w0 + tv[s][p][1].x * w1;
            ay += tv[s][p][0].y * w0 + tv[s][p][1].y * w1;
            az += tv[s][p][0].z * w0 + tv[s][p][1].z * w1;
            aw += tv[s][p][0].w * w0 + tv[s][p][1].w * w1;
        }
        // sum u0/u1 partials across the usel pair (lane ^ 4); both lanes get the sum
        ax += __shfl_xor(ax, 4, 64);
        ay += __shfl_xor(ay, 4, 64);
        az += __shfl_xor(az, 4, 64);
        aw += __shfl_xor(aw, 4, 64);
        res[p] = make_float4(ax, ay, az, aw);
    }

    // out layout: point i, plane p, feature f -> out[i*48 + p*16 + fg*4 ..]
    f4v* o4 = (f4v*)out;
    long ob = (long)i * 12;
    if (usel == 0) {
        f4v r0 = {res[0].x, res[0].y, res[0].z, res[0].w};
        f4v r2 = {res[2].x, res[2].y, res[2].z, res[2].w};
        __builtin_nontemporal_store(r0, &o4[ob + 0 + fg]);
        __builtin_nontemporal_store(r2, &o4[ob + 8 + fg]);
    } else {
        f4v r1 = {res[1].x, res[1].y, res[1].z, res[1].w};
        __builtin_nontemporal_store(r1, &o4[ob + 4 + fg]);
    }
}

extern "C" void kernel_launch(void* const* d_in, const int* in_sizes, int n_in,
                              void* d_out, int out_size, void* d_ws, size_t ws_size,
                              hipStream_t stream) {
    const float* x     = (const float*)d_in[0];
    const float* level = (const float*)d_in[1];
    const float* tex   = (const float*)d_in[2];
    float* out = (float*)d_out;
    float* ws  = (float*)d_ws;
    int n = in_sizes[0] / 3;

    // Build mip pyramid: level k from level k-1.
    const float* src = tex;
    for (int k = 1; k < NLEV; ++k) {
        int r2 = BASE >> k;
        float* dst = ws + mip_off(k);
        int total = 3 * r2 * r2 * 4;
        int blocks = (total + 255) / 256;
        ds_kernel<<<blocks, 256, 0, stream>>>(src, dst, r2);
        src = dst;
    }

    long tt = (long)n * 8;
    int blocks = (int)((tt + 255) / 256);
    tm_sample8<<<blocks, 256, 0, stream>>>(x, level, tex, ws, out, n);
}

// Round 4
// 152.858 us; speedup vs baseline: 1.1147x; 1.0407x over previous
//
#include <hip/hip_runtime.h>
#include <hip/hip_fp16.h>

#define NLEV 8
#define BASE 512

typedef _Float16 h8 __attribute__((ext_vector_type(8)));
typedef float f4v __attribute__((ext_vector_type(4)));

// half-offset of fp16 mip level k (k in [1,7]) within ws; texel = 16 halves.
__host__ __device__ __forceinline__ long moff(int k) {
    return 4194304L - (4194304L >> (2 * k - 2));
}
#define MIPS_HALVES 4194048L           // moff(8)
#define L0_OFF      MIPS_HALVES        // fp16 copy of level 0 lives after the mips
#define L0_HALVES   12582912L          // 3*512*512*16
#define WS_NEED_FULL ((L0_OFF + L0_HALVES) * 2)

// Convert f32 level-0 texture -> fp16 copy. One thread per 8 floats.
__global__ __launch_bounds__(256) void cvt0(const float* __restrict__ src,
                                            _Float16* __restrict__ dst) {
    long idx = (long)blockIdx.x * blockDim.x + threadIdx.x;
    if (idx >= L0_HALVES / 8) return;
    const f4v* s = (const f4v*)src;
    f4v a = s[idx * 2], b = s[idx * 2 + 1];
    h8 o;
    o[0] = (_Float16)a[0]; o[1] = (_Float16)a[1]; o[2] = (_Float16)a[2]; o[3] = (_Float16)a[3];
    o[4] = (_Float16)b[0]; o[5] = (_Float16)b[1]; o[6] = (_Float16)b[2]; o[7] = (_Float16)b[3];
    ((h8*)dst)[idx] = o;
}

// Build mip1 (fp16) directly from the f32 texture: one thread per 8-feature
// half of one output texel.
__global__ __launch_bounds__(256) void ds16_first(const float* __restrict__ src,
                                                  _Float16* __restrict__ dst, int r2) {
    int idx = blockIdx.x * blockDim.x + threadIdx.x;
    int total = 3 * r2 * r2 * 2;
    if (idx >= total) return;
    int g = idx & 1;
    int rest = idx >> 1;
    int u = rest % r2; rest /= r2;
    int v = rest % r2;
    int p = rest / r2;
    int rs = r2 * 2;
    const f4v* s4 = (const f4v*)src;
    long t00 = ((long)p * rs + 2 * v) * rs + 2 * u;   // src texel index
    long t01 = t00 + 1, t10 = t00 + rs, t11 = t10 + 1;
    f4v a0 = s4[t00 * 4 + g * 2], a1 = s4[t00 * 4 + g * 2 + 1];
    f4v b0 = s4[t01 * 4 + g * 2], b1 = s4[t01 * 4 + g * 2 + 1];
    f4v c0 = s4[t10 * 4 + g * 2], c1 = s4[t10 * 4 + g * 2 + 1];
    f4v d0 = s4[t11 * 4 + g * 2], d1 = s4[t11 * 4 + g * 2 + 1];
    h8 o;
#pragma unroll
    for (int j = 0; j < 4; ++j) {
        o[j]     = (_Float16)((a0[j] + b0[j] + c0[j] + d0[j]) * 0.25f);
        o[4 + j] = (_Float16)((a1[j] + b1[j] + c1[j] + d1[j]) * 0.25f);
    }
    ((h8*)dst)[idx] = o;
}

// Downsample fp16 mip -> fp16 mip (accumulate in f32).
__global__ __launch_bounds__(256) void ds16(const _Float16* __restrict__ src,
                                            _Float16* __restrict__ dst, int r2) {
    int idx = blockIdx.x * blockDim.x + threadIdx.x;
    int total = 3 * r2 * r2 * 2;
    if (idx >= total) return;
    int g = idx & 1;
    int rest = idx >> 1;
    int u = rest % r2; rest /= r2;
    int v = rest % r2;
    int p = rest / r2;
    int rs = r2 * 2;
    const h8* s8 = (const h8*)src;
    long t00 = ((long)p * rs + 2 * v) * rs + 2 * u;
    long t01 = t00 + 1, t10 = t00 + rs, t11 = t10 + 1;
    h8 A = s8[t00 * 2 + g], B = s8[t01 * 2 + g], C = s8[t10 * 2 + g], D = s8[t11 * 2 + g];
    h8 o;
#pragma unroll
    for (int j = 0; j < 8; ++j)
        o[j] = (_Float16)(((float)A[j] + (float)B[j] + (float)C[j] + (float)D[j]) * 0.25f);
    ((h8*)dst)[idx] = o;
}

// Sampling: 4 lanes per point. lane = i*4 + usel*2 + fg.
// fg owns 8 features (16 B fp16); usel owns the u-column. The 4 lanes of a
// point read one contiguous 64 B line per (level, plane, vrow) when u1=u0+1.
template <bool L0F16>
__global__ __launch_bounds__(256) void tm_sample4(const float* __restrict__ x,
                                                  const float* __restrict__ level,
                                                  const float* __restrict__ tex0,
                                                  const _Float16* __restrict__ wsh,
                                                  float* __restrict__ out, int n) {
    int t = blockIdx.x * blockDim.x + threadIdx.x;
    int i = t >> 2;
    if (i >= n) return;
    int fg = t & 1;
    int usel = (t >> 1) & 1;

    float px = x[3 * i + 0];
    float py = x[3 * i + 1];
    float pz = x[3 * i + 2];
    float lev = fminf(fmaxf(level[i], 0.0f), (float)(NLEV - 1));
    float l0f = floorf(lev);
    float frac = lev - l0f;
    int l0 = (int)l0f;
    int k1 = min(l0 + 1, NLEV - 1);    // always >= 1

    float uu[3] = {py, px, px};
    float vv[3] = {pz, pz, py};
    int rr[2] = {BASE >> l0, BASE >> k1};

    const _Float16* texs[2];
    texs[0] = (l0 == 0) ? (wsh + L0_OFF) : (wsh + moff(l0));
    texs[1] = wsh + moff(k1);

    h8 tvh[2][3][2];      // [lev][plane][vrow] this lane's 8 features
    float wu[2][3];       // lane's u weight
    float fvv[2][3];      // v fraction

#pragma unroll
    for (int s = 0; s < 2; ++s) {
        int r = rr[s];
        float rf = (float)r;
        const h8* t8 = (const h8*)texs[s];
        bool f32path = (!L0F16) && (s == 0) && (l0 == 0);
#pragma unroll
        for (int p = 0; p < 3; ++p) {
            float cu = uu[p] * rf - 0.5f;
            float cv = vv[p] * rf - 0.5f;
            float fu0 = floorf(cu), fv0 = floorf(cv);
            float fu = cu - fu0, fv = cv - fv0;
            int iu0 = (int)fu0, iv0 = (int)fv0;
            int u0 = min(max(iu0, 0), r - 1);
            int u1 = min(max(iu0 + 1, 0), r - 1);
            int v0 = min(max(iv0, 0), r - 1);
            int v1 = min(max(iv0 + 1, 0), r - 1);
            int u = usel ? u1 : u0;
            wu[s][p] = usel ? fu : (1.0f - fu);
            fvv[s][p] = fv;
            long pb = (long)p * r * r;
            long ti0 = pb + (long)v0 * r + u;
            long ti1 = pb + (long)v1 * r + u;
            if (f32path) {
                const f4v* t4 = (const f4v*)tex0;
                f4v a = t4[ti0 * 4 + fg * 2], b = t4[ti0 * 4 + fg * 2 + 1];
                f4v c = t4[ti1 * 4 + fg * 2], d = t4[ti1 * 4 + fg * 2 + 1];
                h8 A, B;
#pragma unroll
                for (int j = 0; j < 4; ++j) {
                    A[j] = (_Float16)a[j]; A[4 + j] = (_Float16)b[j];
                    B[j] = (_Float16)c[j]; B[4 + j] = (_Float16)d[j];
                }
                tvh[s][p][0] = A;
                tvh[s][p][1] = B;
            } else {
                tvh[s][p][0] = t8[ti0 * 2 + fg];
                tvh[s][p][1] = t8[ti1 * 2 + fg];
            }
        }
    }

    float lw[2] = {1.0f - frac, frac};
    float acc[3][8];
#pragma unroll
    for (int p = 0; p < 3; ++p)
#pragma unroll
        for (int j = 0; j < 8; ++j) acc[p][j] = 0.f;

#pragma unroll
    for (int s = 0; s < 2; ++s)
#pragma unroll
        for (int p = 0; p < 3; ++p) {
            float w0 = (1.0f - fvv[s][p]) * wu[s][p] * lw[s];
            float w1 = fvv[s][p] * wu[s][p] * lw[s];
#pragma unroll
            for (int j = 0; j < 8; ++j)
                acc[p][j] += (float)tvh[s][p][0][j] * w0 + (float)tvh[s][p][1][j] * w1;
        }

    // merge u0/u1 partials across the usel pair (lane ^ 2)
#pragma unroll
    for (int p = 0; p < 3; ++p)
#pragma unroll
        for (int j = 0; j < 8; ++j)
            acc[p][j] += __shfl_xor(acc[p][j], 2, 64);

    // out[i*48 + p*16 + fg*8 + j]; as f4v: index i*12 + p*4 + fg*2 (+1)
    f4v* o4 = (f4v*)out;
    long ob = (long)i * 12 + fg * 2;
    if (usel == 0) {
        f4v r0 = {acc[0][0], acc[0][1], acc[0][2], acc[0][3]};
        f4v r1 = {acc[0][4], acc[0][5], acc[0][6], acc[0][7]};
        f4v r4 = {acc[2][0], acc[2][1], acc[2][2], acc[2][3]};
        f4v r5 = {acc[2][4], acc[2][5], acc[2][6], acc[2][7]};
        __builtin_nontemporal_store(r0, &o4[ob + 0]);
        __builtin_nontemporal_store(r1, &o4[ob + 1]);
        __builtin_nontemporal_store(r4, &o4[ob + 8]);
        __builtin_nontemporal_store(r5, &o4[ob + 9]);
    } else {
        f4v r2 = {acc[1][0], acc[1][1], acc[1][2], acc[1][3]};
        f4v r3 = {acc[1][4], acc[1][5], acc[1][6], acc[1][7]};
        __builtin_nontemporal_store(r2, &o4[ob + 4]);
        __builtin_nontemporal_store(r3, &o4[ob + 5]);
    }
}

extern "C" void kernel_launch(void* const* d_in, const int* in_sizes, int n_in,
                              void* d_out, int out_size, void* d_ws, size_t ws_size,
                              hipStream_t stream) {
    const float* x     = (const float*)d_in[0];
    const float* level = (const float*)d_in[1];
    const float* tex   = (const float*)d_in[2];
    float* out = (float*)d_out;
    _Float16* wsh = (_Float16*)d_ws;
    int n = in_sizes[0] / 3;

    bool full = ws_size >= (size_t)WS_NEED_FULL;

    // mip 1 from f32 texture
    {
        int r2 = BASE >> 1;
        int total = 3 * r2 * r2 * 2;
        ds16_first<<<(total + 255) / 256, 256, 0, stream>>>(tex, wsh + moff(1), r2);
    }
    // mips 2..7 from previous fp16 mip
    for (int k = 2; k < NLEV; ++k) {
        int r2 = BASE >> k;
        int total = 3 * r2 * r2 * 2;
        ds16<<<(total + 255) / 256, 256, 0, stream>>>(wsh + moff(k - 1), wsh + moff(k), r2);
    }
    // fp16 copy of level 0 (only if workspace fits)
    if (full) {
        long tot = L0_HALVES / 8;
        cvt0<<<(int)((tot + 255) / 256), 256, 0, stream>>>(tex, wsh + L0_OFF);
    }

    long tt = (long)n * 4;
    int blocks = (int)((tt + 255) / 256);
    if (full)
        tm_sample4<true><<<blocks, 256, 0, stream>>>(x, level, tex, wsh, out, n);
    else
        tm_sample4<false><<<blocks, 256, 0, stream>>>(x, level, tex, wsh, out, n);
}